// Round 4
// baseline (137.949 us; speedup 1.0000x reference)
//
#include <hip/hip_runtime.h>
#include <math.h>

typedef unsigned int uint32;
typedef short short8 __attribute__((ext_vector_type(8)));   // 8 bf16 (4 VGPRs)
typedef float f32x4 __attribute__((ext_vector_type(4)));    // MFMA accumulator

union frag_u { short8 s; uint32 u[4]; uint4 q; };

// ---------------------------------------------------------------------------
// SparseMHA: bf16-MFMA Q/K/V projection (LDS-free, h-in-registers) + fused
//   sparse attention (SDDMM -> no-max exp2 softmax -> SPMM), wave per node.
// reshape(n,16,8) => flat idx = d*8+h, head = idx%8.
// Packed pair: u32 at [node*64+c] = (bf16(x[c]), bf16(x[c+64])).
// KV rows interleaved as uint2 so the edge gather is one 8B load per lane.
// Q pre-scaled by 16^-0.5 * log2(e) so p = exp2(q.k) is the softmax exp.
// ---------------------------------------------------------------------------

__device__ __forceinline__ uint32 pack_bf16(float lo, float hi) {
    uint32 a = __float_as_uint(lo);
    uint32 b = __float_as_uint(hi);
    a = (a + 0x7FFFu + ((a >> 16) & 1u)) >> 16;          // RNE
    b = (b + 0x7FFFu + ((b >> 16) & 1u)) & 0xFFFF0000u;  // RNE
    return a | b;
}
__device__ __forceinline__ unsigned short bf16r(float x) {
    uint32 u = __float_as_uint(x);
    return (unsigned short)((u + 0x7FFFu + ((u >> 16) & 1u)) >> 16);
}

// ---- one-time: Wt[mat][n][kpair] = bf16 pairs of W[k][n] ------------------
__global__ __launch_bounds__(256) void transpose_W_kernel(
    const float* __restrict__ Wq, const float* __restrict__ Wk,
    const float* __restrict__ Wv, uint32* __restrict__ Wt)
{
    __shared__ unsigned short tile[128][129];
    const int m = blockIdx.x;
    const float* W = (m == 0) ? Wq : (m == 1) ? Wk : Wv;
    const int t = threadIdx.x;

    const float4* W4 = reinterpret_cast<const float4*>(W);
    #pragma unroll
    for (int i0 = 0; i0 < 16; ++i0) {
        int i = t + i0 * 256;                 // 4096 float4
        int k = i >> 5, nq = i & 31;
        float4 v = W4[i];
        tile[nq * 4 + 0][k] = bf16r(v.x);
        tile[nq * 4 + 1][k] = bf16r(v.y);
        tile[nq * 4 + 2][k] = bf16r(v.z);
        tile[nq * 4 + 3][k] = bf16r(v.w);
    }
    __syncthreads();
    uint32* out = Wt + (size_t)m * 8192;
    #pragma unroll
    for (int i0 = 0; i0 < 32; ++i0) {
        int i = t + i0 * 256;                 // 8192 u32 kpairs: [n][kp]
        int n = i >> 6, kp = i & 63;
        out[i] = (uint32)tile[n][kp * 2] | ((uint32)tile[n][kp * 2 + 1] << 16);
    }
}

// ---- LDS-free MFMA projection: 64 nodes/block, all 3 mats -----------------
__global__ __launch_bounds__(256) void proj_mfma_kernel(
    const float* __restrict__ h, const uint32* __restrict__ Wt,
    const float* __restrict__ bq, const float* __restrict__ bk,
    const float* __restrict__ bv,
    uint32* __restrict__ Qp, uint2* __restrict__ KV, int N)
{
    const int t = threadIdx.x;
    const int lane = t & 63;
    const int wv = t >> 6;               // wave -> node rows wv*16..+15
    const int r = lane & 15, g = lane >> 4;
    const int nbase = blockIdx.x * 64;

    // A fragments in registers, reused for all 3 matrices.
    // afr[kb] = bf16(h[arow][(kb*4+g)*8 .. +8])
    const int arow = nbase + wv * 16 + r;
    const bool av = arow < N;
    const float4* h4 = reinterpret_cast<const float4*>(h);
    frag_u afr[4];
    #pragma unroll
    for (int kb = 0; kb < 4; ++kb) {
        float4 x = make_float4(0.f,0.f,0.f,0.f), y = x;
        if (av) {
            size_t base = (size_t)arow * 32 + (kb * 4 + g) * 2;
            x = h4[base]; y = h4[base + 1];
        }
        afr[kb].u[0] = pack_bf16(x.x, x.y);
        afr[kb].u[1] = pack_bf16(x.z, x.w);
        afr[kb].u[2] = pack_bf16(y.x, y.y);
        afr[kb].u[3] = pack_bf16(y.z, y.w);
    }

    const float SCALE_Q = 0.25f * 1.44269504f;   // 16^-0.5 * log2(e)
    uint32 kpk[4][4];                            // K results held for V epilogue

    #pragma unroll
    for (int mat = 0; mat < 3; ++mat) {
        f32x4 acc[8];
        #pragma unroll
        for (int tt = 0; tt < 8; ++tt) acc[tt] = (f32x4){0.f, 0.f, 0.f, 0.f};

        const uint32* wb = Wt + mat * 8192;
        #pragma unroll
        for (int tt = 0; tt < 8; ++tt) {         // B row = output col tt*16+r
            #pragma unroll
            for (int kb = 0; kb < 4; ++kb) {
                frag_u bfr;
                bfr.q = *reinterpret_cast<const uint4*>(
                            wb + (tt * 16 + r) * 64 + (kb * 4 + g) * 4);
                acc[tt] = __builtin_amdgcn_mfma_f32_16x16x32_bf16(
                              afr[kb].s, bfr.s, acc[tt], 0, 0, 0);
            }
        }

        // C/D map: col = lane&15 (=r), row = g*4 + reg  (m89-verified)
        const float* bias = (mat == 0) ? bq : (mat == 1) ? bk : bv;
        #pragma unroll
        for (int tt = 0; tt < 4; ++tt) {
            int c = tt * 16 + r;                 // pair (c, c+64)
            float blo = bias[c], bhi = bias[c + 64];
            #pragma unroll
            for (int reg = 0; reg < 4; ++reg) {
                int node = nbase + wv * 16 + g * 4 + reg;
                float lo = acc[tt][reg] + blo;
                float hi = acc[tt + 4][reg] + bhi;
                if (mat == 0) {
                    if (node < N)
                        Qp[(size_t)node * 64 + c] = pack_bf16(lo * SCALE_Q, hi * SCALE_Q);
                } else if (mat == 1) {
                    kpk[tt][reg] = pack_bf16(lo, hi);
                } else {
                    if (node < N)
                        KV[(size_t)node * 64 + c] = make_uint2(kpk[tt][reg], pack_bf16(lo, hi));
                }
            }
        }
    }
}

// ---- row_ptr[i] = lower_bound(row, i) ------------------------------------
__global__ void row_ptr_kernel(const int* __restrict__ row, int* __restrict__ rp,
                               int N, int E)
{
    int i = blockIdx.x * blockDim.x + threadIdx.x;
    if (i > N) return;
    int lo = 0, hi = E;
    while (lo < hi) {
        int mid = (lo + hi) >> 1;
        if (row[mid] < i) lo = mid + 1; else hi = mid;
    }
    rp[i] = lo;
}

// ---- fused edge stage: wave per node, 8-deep prefetch, col-ahead ----------
__global__ __launch_bounds__(256) void edge_attn_kernel(
    const uint32* __restrict__ Qp, const uint2* __restrict__ KV,
    const int* __restrict__ rp, const int* __restrict__ col,
    float* __restrict__ out, int N)
{
    const int lane = threadIdx.x & 63;
    const int node = blockIdx.x * 4 + (threadIdx.x >> 6);
    if (node >= N) return;

    const int start = rp[node], end = rp[node + 1];
    float* outp = out + (size_t)node * 128;
    if (start >= end) { outp[lane] = 0.f; outp[lane + 64] = 0.f; return; }
    const int last = end - 1;

    const uint32 qu = Qp[(size_t)node * 64 + lane];
    const float q0 = __uint_as_float(qu << 16);
    const float q1 = __uint_as_float(qu & 0xFFFF0000u);

    float z = 0.f, a0 = 0.f, a1 = 0.f;

    // prologue: cols for group 0 -> KV group 0 in flight -> cols for group 1
    int cb[8];
    #pragma unroll
    for (int d = 0; d < 8; ++d) cb[d] = col[min(start + d, last)];
    uint2 kv[8];
    #pragma unroll
    for (int d = 0; d < 8; ++d) kv[d] = KV[(size_t)cb[d] * 64 + lane];
    #pragma unroll
    for (int d = 0; d < 8; ++d) cb[d] = col[min(start + 8 + d, last)];

    for (int gb = start; gb < end; gb += 8) {
        uint2 kvn[8];
        #pragma unroll
        for (int d = 0; d < 8; ++d)          // issue next group's KV
            kvn[d] = KV[(size_t)cb[d] * 64 + lane];
        #pragma unroll
        for (int d = 0; d < 8; ++d)          // cols two groups ahead
            cb[d] = col[min(gb + 16 + d, last)];
        #pragma unroll
        for (int d = 0; d < 8; ++d) {
            if (gb + d < end) {              // wave-uniform
                const float k0 = __uint_as_float(kv[d].x << 16);
                const float k1 = __uint_as_float(kv[d].x & 0xFFFF0000u);
                const float v0 = __uint_as_float(kv[d].y << 16);
                const float v1 = __uint_as_float(kv[d].y & 0xFFFF0000u);
                float s = fmaf(q0, k0, q1 * k1);
                s += __shfl_xor(s, 8);       // head = idx%8: reduce bits 3..5
                s += __shfl_xor(s, 16);
                s += __shfl_xor(s, 32);
                const float p = __builtin_amdgcn_exp2f(s);
                z += p;
                a0 = fmaf(p, v0, a0);
                a1 = fmaf(p, v1, a1);
            }
        }
        #pragma unroll
        for (int d = 0; d < 8; ++d) kv[d] = kvn[d];
    }

    const float rz = 1.0f / z;
    outp[lane]      = a0 * rz;
    outp[lane + 64] = a1 * rz;
}

extern "C" void kernel_launch(void* const* d_in, const int* in_sizes, int n_in,
                              void* d_out, int out_size, void* d_ws, size_t ws_size,
                              hipStream_t stream)
{
    const float* h  = (const float*)d_in[0];
    const float* Wq = (const float*)d_in[1];
    const float* bq = (const float*)d_in[2];
    const float* Wk = (const float*)d_in[3];
    const float* bk = (const float*)d_in[4];
    const float* Wv = (const float*)d_in[5];
    const float* bv = (const float*)d_in[6];
    const int* row  = (const int*)d_in[7];
    const int* col  = (const int*)d_in[8];
    float* out = (float*)d_out;

    const int N = in_sizes[0] / 128;
    const int E = in_sizes[7];

    // ws: KV (N*64 uint2) | Qp (N*64 u32) | Wt (3*8192 u32) | rp (N+1)
    uint2*  KV = (uint2*)d_ws;
    uint32* Qp = (uint32*)(KV + (size_t)N * 64);
    uint32* Wt = Qp + (size_t)N * 64;
    int*    rp = (int*)(Wt + 3 * 8192);

    transpose_W_kernel<<<3, 256, 0, stream>>>(Wq, Wk, Wv, Wt);
    row_ptr_kernel<<<(N + 256) / 256, 256, 0, stream>>>(row, rp, N, E);
    proj_mfma_kernel<<<(N + 63) / 64, 256, 0, stream>>>(
        h, Wt, bq, bk, bv, Qp, KV, N);
    edge_attn_kernel<<<(N + 3) / 4, 256, 0, stream>>>(Qp, KV, rp, col, out, N);
}

// Round 5
// 110.975 us; speedup vs baseline: 1.2431x; 1.2431x over previous
//
#include <hip/hip_runtime.h>
#include <math.h>

typedef unsigned int uint32;
typedef short short8 __attribute__((ext_vector_type(8)));   // 8 bf16 (4 VGPRs)
typedef float f32x4 __attribute__((ext_vector_type(4)));    // MFMA accumulator

union frag_u { short8 s; uint32 u[4]; uint4 q; };

// ---------------------------------------------------------------------------
// SparseMHA: bf16-MFMA Q/K/V projection (A-in-regs, block reads Wt once) +
// fused sparse attention with lane=(edge-slot, head) decomposition:
//   lane l owns edge slot l>>3 and head l&7; computes the 16-dim per-head dot
//   lane-locally (no per-edge shuffles), one butterfly reduce per node.
// reshape(n,16,8) => flat idx = d*8+h, head = idx%8.
// Packed pair: u32 at [node*64+c] = (bf16(x[c]), bf16(x[c+64])).
//   Head h's 16 dims = pair cols {h+8i, i=0..7} (lo=dim h+8i, hi=dim h+8i+64).
// KV rows interleaved as uint2; Q pre-scaled by 16^-0.5*log2(e) => p=exp2(q.k).
// ---------------------------------------------------------------------------

__device__ __forceinline__ uint32 pack_bf16(float lo, float hi) {
    uint32 a = __float_as_uint(lo);
    uint32 b = __float_as_uint(hi);
    a = (a + 0x7FFFu + ((a >> 16) & 1u)) >> 16;          // RNE
    b = (b + 0x7FFFu + ((b >> 16) & 1u)) & 0xFFFF0000u;  // RNE
    return a | b;
}
__device__ __forceinline__ unsigned short bf16r(float x) {
    uint32 u = __float_as_uint(x);
    return (unsigned short)((u + 0x7FFFu + ((u >> 16) & 1u)) >> 16);
}

// ---- one-time: Wt[mat][n][kpair] = bf16 pairs of W[k][n] ------------------
__global__ __launch_bounds__(256) void transpose_W_kernel(
    const float* __restrict__ Wq, const float* __restrict__ Wk,
    const float* __restrict__ Wv, uint32* __restrict__ Wt)
{
    __shared__ unsigned short tile[128][129];
    const int m = blockIdx.x;
    const float* W = (m == 0) ? Wq : (m == 1) ? Wk : Wv;
    const int t = threadIdx.x;

    const float4* W4 = reinterpret_cast<const float4*>(W);
    #pragma unroll
    for (int i0 = 0; i0 < 16; ++i0) {
        int i = t + i0 * 256;                 // 4096 float4
        int k = i >> 5, nq = i & 31;
        float4 v = W4[i];
        tile[nq * 4 + 0][k] = bf16r(v.x);
        tile[nq * 4 + 1][k] = bf16r(v.y);
        tile[nq * 4 + 2][k] = bf16r(v.z);
        tile[nq * 4 + 3][k] = bf16r(v.w);
    }
    __syncthreads();
    uint32* out = Wt + (size_t)m * 8192;
    #pragma unroll
    for (int i0 = 0; i0 < 32; ++i0) {
        int i = t + i0 * 256;                 // 8192 u32 kpairs: [n][kp]
        int n = i >> 6, kp = i & 63;
        out[i] = (uint32)tile[n][kp * 2] | ((uint32)tile[n][kp * 2 + 1] << 16);
    }
}

// ---- MFMA projection: 64 nodes/block; wave w owns col-tiles {w, w+4} ------
__global__ __launch_bounds__(256) void proj_mfma_kernel(
    const float* __restrict__ h, const uint32* __restrict__ Wt,
    const float* __restrict__ bq, const float* __restrict__ bk,
    const float* __restrict__ bv,
    uint32* __restrict__ Qp, uint2* __restrict__ KV, int N)
{
    const int t = threadIdx.x;
    const int lane = t & 63;
    const int w = t >> 6;                // wave id: cols 16w..+15 and +64
    const int r = lane & 15, g = lane >> 4;
    const int nbase = blockIdx.x * 64;

    // A fragments for all 4 node-groups, reused across 3 mats and 2 col-tiles
    frag_u afr[4][4];                    // [ng][kb]
    const float4* h4 = reinterpret_cast<const float4*>(h);
    #pragma unroll
    for (int ng = 0; ng < 4; ++ng) {
        int arow = nbase + ng * 16 + r;
        bool av = arow < N;
        #pragma unroll
        for (int kb = 0; kb < 4; ++kb) {
            float4 x = make_float4(0.f,0.f,0.f,0.f), y = x;
            if (av) {
                size_t base = (size_t)arow * 32 + (kb * 4 + g) * 2;
                x = h4[base]; y = h4[base + 1];
            }
            afr[ng][kb].u[0] = pack_bf16(x.x, x.y);
            afr[ng][kb].u[1] = pack_bf16(x.z, x.w);
            afr[ng][kb].u[2] = pack_bf16(y.x, y.y);
            afr[ng][kb].u[3] = pack_bf16(y.z, y.w);
        }
    }

    const float SCALE_Q = 0.25f * 1.44269504f;   // 16^-0.5 * log2(e)
    const int c = w * 16 + r;                    // this lane's pair col
    uint32 kpk[4][4];                            // K held for V epilogue

    #pragma unroll
    for (int mat = 0; mat < 3; ++mat) {
        const uint32* wb = Wt + mat * 8192;
        frag_u bfr[2][4];                        // [tti][kb]; tt = w + 4*tti
        #pragma unroll
        for (int tti = 0; tti < 2; ++tti)
            #pragma unroll
            for (int kb = 0; kb < 4; ++kb)
                bfr[tti][kb].q = *reinterpret_cast<const uint4*>(
                    wb + ((w + 4 * tti) * 16 + r) * 64 + (kb * 4 + g) * 4);

        f32x4 acc[4][2];
        #pragma unroll
        for (int ng = 0; ng < 4; ++ng)
            #pragma unroll
            for (int tti = 0; tti < 2; ++tti)
                acc[ng][tti] = (f32x4){0.f, 0.f, 0.f, 0.f};

        #pragma unroll
        for (int ng = 0; ng < 4; ++ng)
            #pragma unroll
            for (int tti = 0; tti < 2; ++tti)
                #pragma unroll
                for (int kb = 0; kb < 4; ++kb)
                    acc[ng][tti] = __builtin_amdgcn_mfma_f32_16x16x32_bf16(
                        afr[ng][kb].s, bfr[tti][kb].s, acc[ng][tti], 0, 0, 0);

        // C/D map: col=lane&15, row=g*4+reg; tti=0 -> col c, tti=1 -> col c+64
        const float* bias = (mat == 0) ? bq : (mat == 1) ? bk : bv;
        float blo = bias[c], bhi = bias[c + 64];
        #pragma unroll
        for (int ng = 0; ng < 4; ++ng) {
            #pragma unroll
            for (int reg = 0; reg < 4; ++reg) {
                int node = nbase + ng * 16 + g * 4 + reg;
                float lo = acc[ng][0][reg] + blo;
                float hi = acc[ng][1][reg] + bhi;
                if (mat == 0) {
                    if (node < N)
                        Qp[(size_t)node * 64 + c] = pack_bf16(lo * SCALE_Q, hi * SCALE_Q);
                } else if (mat == 1) {
                    kpk[ng][reg] = pack_bf16(lo, hi);
                } else {
                    if (node < N)
                        KV[(size_t)node * 64 + c] = make_uint2(kpk[ng][reg], pack_bf16(lo, hi));
                }
            }
        }
    }
}

// ---- row_ptr[i] = lower_bound(row, i) ------------------------------------
__global__ void row_ptr_kernel(const int* __restrict__ row, int* __restrict__ rp,
                               int N, int E)
{
    int i = blockIdx.x * blockDim.x + threadIdx.x;
    if (i > N) return;
    int lo = 0, hi = E;
    while (lo < hi) {
        int mid = (lo + hi) >> 1;
        if (row[mid] < i) lo = mid + 1; else hi = mid;
    }
    rp[i] = lo;
}

// ---- fused edge stage: lane = (edge-slot, head); wave per node ------------
__global__ __launch_bounds__(256) void edge_attn_kernel(
    const uint32* __restrict__ Qp, const uint2* __restrict__ KV,
    const int* __restrict__ rp, const int* __restrict__ col,
    float* __restrict__ out, int N)
{
    const int lane = threadIdx.x & 63;
    const int node = blockIdx.x * 4 + (threadIdx.x >> 6);
    if (node >= N) return;
    const int hh   = lane & 7;      // head
    const int slot = lane >> 3;     // edge slot within group of 8

    const int start = rp[node], end = rp[node + 1];
    float* outp = out + (size_t)node * 128;
    if (start >= end) { outp[lane] = 0.f; outp[lane + 64] = 0.f; return; }
    const int last = end - 1;

    // Q for head hh: 16 dims via 8 u32 pair loads
    float q[16];
    {
        const uint32* qrow = Qp + (size_t)node * 64;
        #pragma unroll
        for (int i = 0; i < 8; ++i) {
            uint32 u = qrow[hh + 8 * i];
            q[2 * i]     = __uint_as_float(u << 16);
            q[2 * i + 1] = __uint_as_float(u & 0xFFFF0000u);
        }
    }

    float z = 0.f;
    float acc[16];
    #pragma unroll
    for (int i = 0; i < 16; ++i) acc[i] = 0.f;

    uint2 bufA[8], bufB[8];
    #define LOADG(buf, c0) { \
        const uint2* kvr = KV + (size_t)(c0) * 64; \
        _Pragma("unroll") \
        for (int i = 0; i < 8; ++i) (buf)[i] = kvr[hh + 8 * i]; }
    #define PROC(buf, gb) { \
        float s = 0.f; \
        _Pragma("unroll") \
        for (int i = 0; i < 8; ++i) { \
            s = fmaf(q[2*i],   __uint_as_float((buf)[i].x << 16), s); \
            s = fmaf(q[2*i+1], __uint_as_float((buf)[i].x & 0xFFFF0000u), s); } \
        float p = ((gb) + slot < end) ? __builtin_amdgcn_exp2f(s) : 0.f; \
        z += p; \
        _Pragma("unroll") \
        for (int i = 0; i < 8; ++i) { \
            acc[i]     = fmaf(p, __uint_as_float((buf)[i].y << 16), acc[i]); \
            acc[8 + i] = fmaf(p, __uint_as_float((buf)[i].y & 0xFFFF0000u), acc[8 + i]); } }

    int cA = col[min(start + slot, last)];
    int cB = col[min(start + 8 + slot, last)];
    LOADG(bufA, cA);
    int gb = start;
    while (true) {
        LOADG(bufB, cB);
        cA = col[min(gb + 16 + slot, last)];
        PROC(bufA, gb);
        gb += 8;
        if (gb >= end) break;
        LOADG(bufA, cA);
        cB = col[min(gb + 16 + slot, last)];
        PROC(bufB, gb);
        gb += 8;
        if (gb >= end) break;
    }

    // butterfly reduce across the 8 edge slots (xor lane bits 3..5)
    #pragma unroll
    for (int m = 8; m <= 32; m <<= 1) {
        z += __shfl_xor(z, m);
        #pragma unroll
        for (int i = 0; i < 16; ++i) acc[i] += __shfl_xor(acc[i], m);
    }

    // out flat idx = d*8 + h: lane writes d=slot and d=slot+8
    const float rz = 1.0f / z;
    outp[lane]      = acc[slot] * rz;
    outp[lane + 64] = acc[8 + slot] * rz;
}

extern "C" void kernel_launch(void* const* d_in, const int* in_sizes, int n_in,
                              void* d_out, int out_size, void* d_ws, size_t ws_size,
                              hipStream_t stream)
{
    const float* h  = (const float*)d_in[0];
    const float* Wq = (const float*)d_in[1];
    const float* bq = (const float*)d_in[2];
    const float* Wk = (const float*)d_in[3];
    const float* bk = (const float*)d_in[4];
    const float* Wv = (const float*)d_in[5];
    const float* bv = (const float*)d_in[6];
    const int* row  = (const int*)d_in[7];
    const int* col  = (const int*)d_in[8];
    float* out = (float*)d_out;

    const int N = in_sizes[0] / 128;
    const int E = in_sizes[7];

    // ws: KV (N*64 uint2) | Qp (N*64 u32) | Wt (3*8192 u32) | rp (N+1)
    uint2*  KV = (uint2*)d_ws;
    uint32* Qp = (uint32*)(KV + (size_t)N * 64);
    uint32* Wt = Qp + (size_t)N * 64;
    int*    rp = (int*)(Wt + 3 * 8192);

    transpose_W_kernel<<<3, 256, 0, stream>>>(Wq, Wk, Wv, Wt);
    row_ptr_kernel<<<(N + 256) / 256, 256, 0, stream>>>(row, rp, N, E);
    proj_mfma_kernel<<<(N + 63) / 64, 256, 0, stream>>>(
        h, Wt, bq, bk, bv, Qp, KV, N);
    edge_attn_kernel<<<(N + 3) / 4, 256, 0, stream>>>(Qp, KV, rp, col, out, N);
}

// Round 7
// 103.782 us; speedup vs baseline: 1.3292x; 1.0693x over previous
//
#include <hip/hip_runtime.h>
#include <math.h>

typedef unsigned int uint32;
typedef _Float16 f16x8 __attribute__((ext_vector_type(8)));   // 8 f16 (4 VGPRs)
typedef _Float16 f16x2 __attribute__((ext_vector_type(2)));
typedef float f32x4 __attribute__((ext_vector_type(4)));      // MFMA accumulator

union frag_u { f16x8 h; uint32 u[4]; uint4 q; };

// ---------------------------------------------------------------------------
// SparseMHA, all-f16 intermediate: prep (W transpose->f16 pairs + row_ptr) ->
// MFMA f16 projection (A-in-regs, block reads Wt once) -> fused edge stage
// with lane=(edge-slot, head): lane l owns edge slot l>>3, head l&7; the
// 16-dim per-head dot is 8 v_dot2_f32_f16, V-accum is v_fma_mix (f16 srcs).
// reshape(n,16,8) => flat idx = d*8+h, head = idx%8.
// Packed pair: u32 at [node*64+c] = (f16(x[c]), f16(x[c+64])).
//   Head h's dims = pair cols {h+8i, i=0..7}.
// KV rows interleaved as uint2; Q pre-scaled by 16^-0.5*log2(e) => p=exp2(q.k).
// ---------------------------------------------------------------------------

__device__ __forceinline__ uint32 pack_f16(float lo, float hi) {
    // v_cvt_pkrtz_f16_f32: 2 f32 -> packed 2 f16, one instruction
    auto r = __builtin_amdgcn_cvt_pkrtz(lo, hi);   // __fp16 ext_vector(2)
    return __builtin_bit_cast(uint32, r);
}
__device__ __forceinline__ float dot2acc(uint32 a, uint32 b, float c) {
#if __has_builtin(__builtin_amdgcn_fdot2)
    return __builtin_amdgcn_fdot2(__builtin_bit_cast(f16x2, a),
                                  __builtin_bit_cast(f16x2, b), c, false);
#else
    f16x2 av = __builtin_bit_cast(f16x2, a), bv = __builtin_bit_cast(f16x2, b);
    return fmaf((float)av[0], (float)bv[0], fmaf((float)av[1], (float)bv[1], c));
#endif
}

// ---- prep: blocks 0..2 transpose W->Wt f16 pairs; rest: row_ptr -----------
__global__ __launch_bounds__(256) void prep_kernel(
    const float* __restrict__ Wq, const float* __restrict__ Wk,
    const float* __restrict__ Wv, uint32* __restrict__ Wt,
    const int* __restrict__ row, int* __restrict__ rp, int N, int E)
{
    const int t = threadIdx.x;
    if (blockIdx.x < 3) {
        __shared__ unsigned short tile[128][129];
        const int m = blockIdx.x;
        const float* W = (m == 0) ? Wq : (m == 1) ? Wk : Wv;
        const float4* W4 = reinterpret_cast<const float4*>(W);
        #pragma unroll
        for (int i0 = 0; i0 < 16; ++i0) {
            int i = t + i0 * 256;                 // 4096 float4
            int k = i >> 5, nq = i & 31;
            float4 v = W4[i];
            tile[nq * 4 + 0][k] = (unsigned short)(pack_f16(v.x, 0.f) & 0xFFFFu);
            tile[nq * 4 + 1][k] = (unsigned short)(pack_f16(v.y, 0.f) & 0xFFFFu);
            tile[nq * 4 + 2][k] = (unsigned short)(pack_f16(v.z, 0.f) & 0xFFFFu);
            tile[nq * 4 + 3][k] = (unsigned short)(pack_f16(v.w, 0.f) & 0xFFFFu);
        }
        __syncthreads();
        uint32* out = Wt + (size_t)m * 8192;
        #pragma unroll
        for (int i0 = 0; i0 < 32; ++i0) {
            int i = t + i0 * 256;                 // 8192 u32 kpairs: [n][kp]
            int n = i >> 6, kp = i & 63;
            out[i] = (uint32)tile[n][kp * 2] | ((uint32)tile[n][kp * 2 + 1] << 16);
        }
    } else {
        int i = (blockIdx.x - 3) * 256 + t;
        if (i > N) return;
        int lo = 0, hi = E;
        while (lo < hi) {
            int mid = (lo + hi) >> 1;
            if (row[mid] < i) lo = mid + 1; else hi = mid;
        }
        rp[i] = lo;
    }
}

// ---- MFMA f16 projection: 64 nodes/block; wave w owns col-tiles {w,w+4} ---
__global__ __launch_bounds__(256) void proj_mfma_kernel(
    const float* __restrict__ h, const uint32* __restrict__ Wt,
    const float* __restrict__ bq, const float* __restrict__ bk,
    const float* __restrict__ bv,
    uint32* __restrict__ Qp, uint2* __restrict__ KV, int N)
{
    const int t = threadIdx.x;
    const int lane = t & 63;
    const int w = t >> 6;                // wave id
    const int r = lane & 15, g = lane >> 4;
    const int nbase = blockIdx.x * 64;

    // A fragments (f16) for all 4 node-groups, reused across 3 mats, 2 tiles
    frag_u afr[4][4];                    // [ng][kb]
    const float4* h4 = reinterpret_cast<const float4*>(h);
    #pragma unroll
    for (int ng = 0; ng < 4; ++ng) {
        int arow = nbase + ng * 16 + r;
        bool av = arow < N;
        #pragma unroll
        for (int kb = 0; kb < 4; ++kb) {
            float4 x = make_float4(0.f,0.f,0.f,0.f), y = x;
            if (av) {
                size_t base = (size_t)arow * 32 + (kb * 4 + g) * 2;
                x = h4[base]; y = h4[base + 1];
            }
            afr[ng][kb].u[0] = pack_f16(x.x, x.y);
            afr[ng][kb].u[1] = pack_f16(x.z, x.w);
            afr[ng][kb].u[2] = pack_f16(y.x, y.y);
            afr[ng][kb].u[3] = pack_f16(y.z, y.w);
        }
    }

    const float SCALE_Q = 0.25f * 1.44269504f;   // 16^-0.5 * log2(e)
    const int c = w * 16 + r;                    // this lane's pair col
    uint32 kpk[4][4];                            // K held for V epilogue

    #pragma unroll
    for (int mat = 0; mat < 3; ++mat) {
        const uint32* wb = Wt + mat * 8192;
        frag_u bfr[2][4];                        // [tti][kb]; tile = w + 4*tti
        #pragma unroll
        for (int tti = 0; tti < 2; ++tti)
            #pragma unroll
            for (int kb = 0; kb < 4; ++kb)
                bfr[tti][kb].q = *reinterpret_cast<const uint4*>(
                    wb + ((w + 4 * tti) * 16 + r) * 64 + (kb * 4 + g) * 4);

        f32x4 acc[4][2];
        #pragma unroll
        for (int ng = 0; ng < 4; ++ng)
            #pragma unroll
            for (int tti = 0; tti < 2; ++tti)
                acc[ng][tti] = (f32x4){0.f, 0.f, 0.f, 0.f};

        #pragma unroll
        for (int ng = 0; ng < 4; ++ng)
            #pragma unroll
            for (int tti = 0; tti < 2; ++tti)
                #pragma unroll
                for (int kb = 0; kb < 4; ++kb)
                    acc[ng][tti] = __builtin_amdgcn_mfma_f32_16x16x32_f16(
                        afr[ng][kb].h, bfr[tti][kb].h, acc[ng][tti], 0, 0, 0);

        // C/D map: col=lane&15, row=g*4+reg; tti=0 -> col c, tti=1 -> c+64
        const float* bias = (mat == 0) ? bq : (mat == 1) ? bk : bv;
        float blo = bias[c], bhi = bias[c + 64];
        #pragma unroll
        for (int ng = 0; ng < 4; ++ng) {
            #pragma unroll
            for (int reg = 0; reg < 4; ++reg) {
                int node = nbase + ng * 16 + g * 4 + reg;
                float lo = acc[ng][0][reg] + blo;
                float hi = acc[ng][1][reg] + bhi;
                if (mat == 0) {
                    if (node < N)
                        Qp[(size_t)node * 64 + c] = pack_f16(lo * SCALE_Q, hi * SCALE_Q);
                } else if (mat == 1) {
                    kpk[ng][reg] = pack_f16(lo, hi);
                } else {
                    if (node < N)
                        KV[(size_t)node * 64 + c] = make_uint2(kpk[ng][reg], pack_f16(lo, hi));
                }
            }
        }
    }
}

// ---- fused edge stage: lane = (edge-slot, head); wave per node ------------
__global__ __launch_bounds__(256) void edge_attn_kernel(
    const uint32* __restrict__ Qp, const uint2* __restrict__ KV,
    const int* __restrict__ rp, const int* __restrict__ col,
    float* __restrict__ out, int N)
{
    const int lane = threadIdx.x & 63;
    const int node = blockIdx.x * 4 + (threadIdx.x >> 6);
    if (node >= N) return;
    const int hh   = lane & 7;      // head
    const int slot = lane >> 3;     // edge slot within group of 8

    const int start = rp[node], end = rp[node + 1];
    float* outp = out + (size_t)node * 128;
    if (start >= end) { outp[lane] = 0.f; outp[lane + 64] = 0.f; return; }
    const int last = end - 1;

    // Q for head hh: 8 packed f16 pairs
    uint32 q[8];
    {
        const uint32* qrow = Qp + (size_t)node * 64;
        #pragma unroll
        for (int i = 0; i < 8; ++i) q[i] = qrow[hh + 8 * i];
    }

    float z = 0.f;
    float acc[16];
    #pragma unroll
    for (int i = 0; i < 16; ++i) acc[i] = 0.f;

    uint2 bufA[8], bufB[8];
    #define LOADG(buf, c0) { \
        const uint2* kvr = KV + (size_t)(c0) * 64; \
        _Pragma("unroll") \
        for (int i = 0; i < 8; ++i) (buf)[i] = kvr[hh + 8 * i]; }
    #define PROC(buf, gb) { \
        float s = 0.f; \
        _Pragma("unroll") \
        for (int i = 0; i < 8; ++i) s = dot2acc(q[i], (buf)[i].x, s); \
        float p = ((gb) + slot < end) ? __builtin_amdgcn_exp2f(s) : 0.f; \
        z += p; \
        _Pragma("unroll") \
        for (int i = 0; i < 8; ++i) { \
            f16x2 hv = __builtin_bit_cast(f16x2, (buf)[i].y); \
            acc[i]     = fmaf(p, (float)hv[0], acc[i]); \
            acc[8 + i] = fmaf(p, (float)hv[1], acc[8 + i]); } }

    int cA = col[min(start + slot, last)];
    int cB = col[min(start + 8 + slot, last)];
    LOADG(bufA, cA);
    int gb = start;
    while (true) {
        LOADG(bufB, cB);
        cA = col[min(gb + 16 + slot, last)];
        PROC(bufA, gb);
        gb += 8;
        if (gb >= end) break;
        LOADG(bufA, cA);
        cB = col[min(gb + 16 + slot, last)];
        PROC(bufB, gb);
        gb += 8;
        if (gb >= end) break;
    }

    // butterfly reduce across the 8 edge slots (xor lane bits 3..5)
    #pragma unroll
    for (int m = 8; m <= 32; m <<= 1) {
        z += __shfl_xor(z, m);
        #pragma unroll
        for (int i = 0; i < 16; ++i) acc[i] += __shfl_xor(acc[i], m);
    }

    // out flat idx = d*8 + h: lane writes d=slot and d=slot+8
    const float rz = 1.0f / z;
    outp[lane]      = acc[slot] * rz;
    outp[lane + 64] = acc[8 + slot] * rz;
}

extern "C" void kernel_launch(void* const* d_in, const int* in_sizes, int n_in,
                              void* d_out, int out_size, void* d_ws, size_t ws_size,
                              hipStream_t stream)
{
    const float* h  = (const float*)d_in[0];
    const float* Wq = (const float*)d_in[1];
    const float* bq = (const float*)d_in[2];
    const float* Wk = (const float*)d_in[3];
    const float* bk = (const float*)d_in[4];
    const float* Wv = (const float*)d_in[5];
    const float* bv = (const float*)d_in[6];
    const int* row  = (const int*)d_in[7];
    const int* col  = (const int*)d_in[8];
    float* out = (float*)d_out;

    const int N = in_sizes[0] / 128;
    const int E = in_sizes[7];

    // ws: KV (N*64 uint2) | Qp (N*64 u32) | Wt (3*8192 u32) | rp (N+1)
    uint2*  KV = (uint2*)d_ws;
    uint32* Qp = (uint32*)(KV + (size_t)N * 64);
    uint32* Wt = Qp + (size_t)N * 64;
    int*    rp = (int*)(Wt + 3 * 8192);

    const int rp_blocks = (N + 1 + 255) / 256;
    prep_kernel<<<3 + rp_blocks, 256, 0, stream>>>(Wq, Wk, Wv, Wt, row, rp, N, E);
    proj_mfma_kernel<<<(N + 63) / 64, 256, 0, stream>>>(
        h, Wt, bq, bk, bv, Qp, KV, N);
    edge_attn_kernel<<<(N + 3) / 4, 256, 0, stream>>>(Qp, KV, rp, col, out, N);
}

// Round 8
// 102.100 us; speedup vs baseline: 1.3511x; 1.0165x over previous
//
#include <hip/hip_runtime.h>
#include <math.h>

typedef unsigned int uint32;
typedef _Float16 f16x8 __attribute__((ext_vector_type(8)));   // 8 f16 (4 VGPRs)
typedef _Float16 f16x2 __attribute__((ext_vector_type(2)));
typedef float f32x4 __attribute__((ext_vector_type(4)));      // MFMA accumulator

union frag_u { f16x8 h; uint32 u[4]; uint4 q; };

// ---------------------------------------------------------------------------
// SparseMHA, all-f16 intermediate:
//   prep: W transpose -> f16 kpairs (3 blocks)
//   proj: MFMA f16, wave owns 32 rows x all 128 cols x 3 mats (A loaded once);
//         trailing blocks of the same grid compute row_ptr (independent work)
//   edge: lane=(edge-slot, head), fdot2 dots, 2-wave blocks, double-buffered
// reshape(n,16,8) => flat idx = d*8+h, head = idx%8.
// Packed pair: u32 at [node*64+c] = (f16(x[c]), f16(x[c+64])).
//   Head h's dims = pair cols {h+8i, i=0..7}.
// KV rows interleaved as uint2; Q pre-scaled by 16^-0.5*log2(e) => p=exp2(q.k).
// ---------------------------------------------------------------------------

__device__ __forceinline__ uint32 pack_f16(float lo, float hi) {
    auto r = __builtin_amdgcn_cvt_pkrtz(lo, hi);   // one v_cvt_pkrtz_f16_f32
    return __builtin_bit_cast(uint32, r);
}
__device__ __forceinline__ float dot2acc(uint32 a, uint32 b, float c) {
#if __has_builtin(__builtin_amdgcn_fdot2)
    return __builtin_amdgcn_fdot2(__builtin_bit_cast(f16x2, a),
                                  __builtin_bit_cast(f16x2, b), c, false);
#else
    f16x2 av = __builtin_bit_cast(f16x2, a), bv = __builtin_bit_cast(f16x2, b);
    return fmaf((float)av[0], (float)bv[0], fmaf((float)av[1], (float)bv[1], c));
#endif
}

// ---- prep: transpose W -> Wt f16 kpairs [n][kp] ---------------------------
__global__ __launch_bounds__(256) void prep_kernel(
    const float* __restrict__ Wq, const float* __restrict__ Wk,
    const float* __restrict__ Wv, uint32* __restrict__ Wt)
{
    const int t = threadIdx.x;
    __shared__ unsigned short tile[128][129];
    const int m = blockIdx.x;
    const float* W = (m == 0) ? Wq : (m == 1) ? Wk : Wv;
    const float4* W4 = reinterpret_cast<const float4*>(W);
    #pragma unroll
    for (int i0 = 0; i0 < 16; ++i0) {
        int i = t + i0 * 256;                 // 4096 float4
        int k = i >> 5, nq = i & 31;
        float4 v = W4[i];
        tile[nq * 4 + 0][k] = (unsigned short)(pack_f16(v.x, 0.f) & 0xFFFFu);
        tile[nq * 4 + 1][k] = (unsigned short)(pack_f16(v.y, 0.f) & 0xFFFFu);
        tile[nq * 4 + 2][k] = (unsigned short)(pack_f16(v.z, 0.f) & 0xFFFFu);
        tile[nq * 4 + 3][k] = (unsigned short)(pack_f16(v.w, 0.f) & 0xFFFFu);
    }
    __syncthreads();
    uint32* out = Wt + (size_t)m * 8192;
    #pragma unroll
    for (int i0 = 0; i0 < 32; ++i0) {
        int i = t + i0 * 256;                 // 8192 u32 kpairs: [n][kp]
        int n = i >> 6, kp = i & 63;
        out[i] = (uint32)tile[n][kp * 2] | ((uint32)tile[n][kp * 2 + 1] << 16);
    }
}

// ---- proj (blocks < PB): wave owns 32 rows; blocks >= PB: row_ptr ---------
__global__ __launch_bounds__(256) void proj_mfma_kernel(
    const float* __restrict__ h, const uint32* __restrict__ Wt,
    const float* __restrict__ bq, const float* __restrict__ bk,
    const float* __restrict__ bv,
    uint32* __restrict__ Qp, uint2* __restrict__ KV,
    const int* __restrict__ row, int* __restrict__ rp,
    int N, int E, int PB)
{
    const int t = threadIdx.x;
    if ((int)blockIdx.x >= PB) {             // ---- row_ptr tail blocks ----
        int i = ((int)blockIdx.x - PB) * 256 + t;
        if (i > N) return;
        int lo = 0, hi = E;
        while (lo < hi) {
            int mid = (lo + hi) >> 1;
            if (row[mid] < i) lo = mid + 1; else hi = mid;
        }
        rp[i] = lo;
        return;
    }

    const int lane = t & 63;
    const int w = t >> 6;
    const int r = lane & 15, g = lane >> 4;
    const int rbase = blockIdx.x * 128 + w * 32;   // this wave's 32 rows

    // A fragments (f16), loaded exactly once per wave
    frag_u afr[2][4];                    // [ng][kb]
    const float4* h4 = reinterpret_cast<const float4*>(h);
    #pragma unroll
    for (int ng = 0; ng < 2; ++ng) {
        int arow = rbase + ng * 16 + r;
        bool av = arow < N;
        #pragma unroll
        for (int kb = 0; kb < 4; ++kb) {
            float4 x = make_float4(0.f,0.f,0.f,0.f), y = x;
            if (av) {
                size_t base = (size_t)arow * 32 + (kb * 4 + g) * 2;
                x = h4[base]; y = h4[base + 1];
            }
            afr[ng][kb].u[0] = pack_f16(x.x, x.y);
            afr[ng][kb].u[1] = pack_f16(x.z, x.w);
            afr[ng][kb].u[2] = pack_f16(y.x, y.y);
            afr[ng][kb].u[3] = pack_f16(y.z, y.w);
        }
    }

    const float SCALE_Q = 0.25f * 1.44269504f;   // 16^-0.5 * log2(e)

    #pragma unroll
    for (int tp = 0; tp < 4; ++tp) {             // col-tile pair {tp, tp+4}
        const int c = tp * 16 + r;               // pair col (c, c+64)
        uint32 kpk[2][4];                        // K held for V epilogue
        #pragma unroll
        for (int mat = 0; mat < 3; ++mat) {
            const uint32* wb = Wt + mat * 8192;
            frag_u bfr[2][4];
            #pragma unroll
            for (int tti = 0; tti < 2; ++tti)
                #pragma unroll
                for (int kb = 0; kb < 4; ++kb)
                    bfr[tti][kb].q = *reinterpret_cast<const uint4*>(
                        wb + ((tp + 4 * tti) * 16 + r) * 64 + (kb * 4 + g) * 4);

            f32x4 acc[2][2];
            #pragma unroll
            for (int ng = 0; ng < 2; ++ng)
                #pragma unroll
                for (int tti = 0; tti < 2; ++tti)
                    acc[ng][tti] = (f32x4){0.f, 0.f, 0.f, 0.f};

            #pragma unroll
            for (int ng = 0; ng < 2; ++ng)
                #pragma unroll
                for (int tti = 0; tti < 2; ++tti)
                    #pragma unroll
                    for (int kb = 0; kb < 4; ++kb)
                        acc[ng][tti] = __builtin_amdgcn_mfma_f32_16x16x32_f16(
                            afr[ng][kb].h, bfr[tti][kb].h, acc[ng][tti], 0, 0, 0);

            // C/D map: col=lane&15, row=g*4+reg
            const float* bias = (mat == 0) ? bq : (mat == 1) ? bk : bv;
            float blo = bias[c], bhi = bias[c + 64];
            #pragma unroll
            for (int ng = 0; ng < 2; ++ng) {
                #pragma unroll
                for (int reg = 0; reg < 4; ++reg) {
                    int node = rbase + ng * 16 + g * 4 + reg;
                    float lo = acc[ng][0][reg] + blo;
                    float hi = acc[ng][1][reg] + bhi;
                    if (mat == 0) {
                        if (node < N)
                            Qp[(size_t)node * 64 + c] = pack_f16(lo * SCALE_Q, hi * SCALE_Q);
                    } else if (mat == 1) {
                        kpk[ng][reg] = pack_f16(lo, hi);
                    } else {
                        if (node < N)
                            KV[(size_t)node * 64 + c] = make_uint2(kpk[ng][reg], pack_f16(lo, hi));
                    }
                }
            }
        }
    }
}

// ---- fused edge stage: lane = (edge-slot, head); 2-wave blocks ------------
__global__ __launch_bounds__(128) void edge_attn_kernel(
    const uint32* __restrict__ Qp, const uint2* __restrict__ KV,
    const int* __restrict__ rp, const int* __restrict__ col,
    float* __restrict__ out, int N)
{
    const int lane = threadIdx.x & 63;
    const int node = blockIdx.x * 2 + (threadIdx.x >> 6);
    if (node >= N) return;
    const int hh   = lane & 7;      // head
    const int slot = lane >> 3;     // edge slot within group of 8

    const int start = rp[node], end = rp[node + 1];
    float* outp = out + (size_t)node * 128;
    if (start >= end) { outp[lane] = 0.f; outp[lane + 64] = 0.f; return; }
    const int last = end - 1;

    // Q for head hh: 8 packed f16 pairs (broadcast across slots)
    uint32 q[8];
    {
        const uint32* qrow = Qp + (size_t)node * 64;
        #pragma unroll
        for (int i = 0; i < 8; ++i) q[i] = qrow[hh + 8 * i];
    }

    float z = 0.f;
    float acc[16];
    #pragma unroll
    for (int i = 0; i < 16; ++i) acc[i] = 0.f;

    uint2 bufA[8], bufB[8];
    #define LOADG(buf, c0) { \
        const uint2* kvr = KV + (size_t)(c0) * 64; \
        _Pragma("unroll") \
        for (int i = 0; i < 8; ++i) (buf)[i] = kvr[hh + 8 * i]; }
    #define PROC(buf, gb) { \
        float s = 0.f; \
        _Pragma("unroll") \
        for (int i = 0; i < 8; ++i) s = dot2acc(q[i], (buf)[i].x, s); \
        float p = ((gb) + slot < end) ? __builtin_amdgcn_exp2f(s) : 0.f; \
        z += p; \
        _Pragma("unroll") \
        for (int i = 0; i < 8; ++i) { \
            f16x2 hv = __builtin_bit_cast(f16x2, (buf)[i].y); \
            acc[i]     = fmaf(p, (float)hv[0], acc[i]); \
            acc[8 + i] = fmaf(p, (float)hv[1], acc[8 + i]); } }

    int cA = col[min(start + slot, last)];
    int cB = col[min(start + 8 + slot, last)];
    LOADG(bufA, cA);
    int gb = start;
    while (true) {
        LOADG(bufB, cB);
        cA = col[min(gb + 16 + slot, last)];
        PROC(bufA, gb);
        gb += 8;
        if (gb >= end) break;
        LOADG(bufA, cA);
        cB = col[min(gb + 16 + slot, last)];
        PROC(bufB, gb);
        gb += 8;
        if (gb >= end) break;
    }

    // butterfly reduce across the 8 edge slots (xor lane bits 3..5)
    #pragma unroll
    for (int m = 8; m <= 32; m <<= 1) {
        z += __shfl_xor(z, m);
        #pragma unroll
        for (int i = 0; i < 16; ++i) acc[i] += __shfl_xor(acc[i], m);
    }

    // out flat idx = d*8 + h: lane writes d=slot and d=slot+8
    const float rz = 1.0f / z;
    outp[lane]      = acc[slot] * rz;
    outp[lane + 64] = acc[8 + slot] * rz;
}

extern "C" void kernel_launch(void* const* d_in, const int* in_sizes, int n_in,
                              void* d_out, int out_size, void* d_ws, size_t ws_size,
                              hipStream_t stream)
{
    const float* h  = (const float*)d_in[0];
    const float* Wq = (const float*)d_in[1];
    const float* bq = (const float*)d_in[2];
    const float* Wk = (const float*)d_in[3];
    const float* bk = (const float*)d_in[4];
    const float* Wv = (const float*)d_in[5];
    const float* bv = (const float*)d_in[6];
    const int* row  = (const int*)d_in[7];
    const int* col  = (const int*)d_in[8];
    float* out = (float*)d_out;

    const int N = in_sizes[0] / 128;
    const int E = in_sizes[7];

    // ws: KV (N*64 uint2) | Qp (N*64 u32) | Wt (3*8192 u32) | rp (N+1)
    uint2*  KV = (uint2*)d_ws;
    uint32* Qp = (uint32*)(KV + (size_t)N * 64);
    uint32* Wt = Qp + (size_t)N * 64;
    int*    rp = (int*)(Wt + 3 * 8192);

    const int PB = (N + 127) / 128;              // proj blocks
    const int rp_blocks = (N + 1 + 255) / 256;   // row_ptr tail blocks

    prep_kernel<<<3, 256, 0, stream>>>(Wq, Wk, Wv, Wt);
    proj_mfma_kernel<<<PB + rp_blocks, 256, 0, stream>>>(
        h, Wt, bq, bk, bv, Qp, KV, row, rp, N, E, PB);
    edge_attn_kernel<<<(N + 1) / 2, 128, 0, stream>>>(Qp, KV, rp, col, out, N);
}

// Round 9
// 89.851 us; speedup vs baseline: 1.5353x; 1.1363x over previous
//
#include <hip/hip_runtime.h>
#include <math.h>

typedef unsigned int uint32;
typedef _Float16 f16x8 __attribute__((ext_vector_type(8)));   // 8 f16 (4 VGPRs)
typedef _Float16 f16x2 __attribute__((ext_vector_type(2)));
typedef float f32x4 __attribute__((ext_vector_type(4)));      // MFMA accumulator

union frag_u { f16x8 h; uint32 u[4]; uint4 q; };

// ---------------------------------------------------------------------------
// SparseMHA, all-f16 intermediate, TWO launches:
//   proj: per-block LDS transpose of W (one mat at a time, 32KB, swizzled)
//         -> MFMA f16, wave owns 32 rows x 128 cols x 3 mats (A loaded once);
//         trailing blocks of the same grid compute row_ptr.
//   edge: lane=(edge-slot, head), fdot2 dots, 2-wave blocks, double-buffered.
// reshape(n,16,8) => flat idx = d*8+h, head = idx%8.
// Packed pair: u32 at [node*64+c] = (f16(x[c]), f16(x[c+64])).
//   Head h's dims = pair cols {h+8i, i=0..7}.
// KV rows interleaved as uint2; Q pre-scaled by 16^-0.5*log2(e) => p=exp2(q.k).
// ---------------------------------------------------------------------------

__device__ __forceinline__ uint32 pack_f16(float lo, float hi) {
    auto r = __builtin_amdgcn_cvt_pkrtz(lo, hi);   // one v_cvt_pkrtz_f16_f32
    return __builtin_bit_cast(uint32, r);
}
__device__ __forceinline__ float dot2acc(uint32 a, uint32 b, float c) {
#if __has_builtin(__builtin_amdgcn_fdot2)
    return __builtin_amdgcn_fdot2(__builtin_bit_cast(f16x2, a),
                                  __builtin_bit_cast(f16x2, b), c, false);
#else
    f16x2 av = __builtin_bit_cast(f16x2, a), bv = __builtin_bit_cast(f16x2, b);
    return fmaf((float)av[0], (float)bv[0], fmaf((float)av[1], (float)bv[1], c));
#endif
}

// ---- proj (blocks < PB): in-block W transpose + MFMA; else row_ptr --------
__global__ __launch_bounds__(256) void proj_mfma_kernel(
    const float* __restrict__ h,
    const float* __restrict__ Wq, const float* __restrict__ Wk,
    const float* __restrict__ Wv,
    const float* __restrict__ bq, const float* __restrict__ bk,
    const float* __restrict__ bv,
    uint32* __restrict__ Qp, uint2* __restrict__ KV,
    const int* __restrict__ row, int* __restrict__ rp,
    int N, int E, int PB)
{
    const int t = threadIdx.x;
    if ((int)blockIdx.x >= PB) {             // ---- row_ptr tail blocks ----
        int i = ((int)blockIdx.x - PB) * 256 + t;
        if (i > N) return;
        int lo = 0, hi = E;
        while (lo < hi) {
            int mid = (lo + hi) >> 1;
            if (row[mid] < i) lo = mid + 1; else hi = mid;
        }
        rp[i] = lo;
        return;
    }

    // LDS: one matrix of Wt, u32 kpairs [n][slot^swz][rem], 32 KB
    __shared__ uint32 Wl[8192];

    const int lane = t & 63;
    const int w = t >> 6;
    const int r = lane & 15, g = lane >> 4;
    const int rbase = blockIdx.x * 128 + w * 32;   // this wave's 32 rows

    // A fragments (f16), loaded exactly once per wave
    frag_u afr[2][4];                    // [ng][kb]
    const float4* h4 = reinterpret_cast<const float4*>(h);
    #pragma unroll
    for (int ng = 0; ng < 2; ++ng) {
        int arow = rbase + ng * 16 + r;
        bool av = arow < N;
        #pragma unroll
        for (int kb = 0; kb < 4; ++kb) {
            float4 x = make_float4(0.f,0.f,0.f,0.f), y = x;
            if (av) {
                size_t base = (size_t)arow * 32 + (kb * 4 + g) * 2;
                x = h4[base]; y = h4[base + 1];
            }
            afr[ng][kb].u[0] = pack_f16(x.x, x.y);
            afr[ng][kb].u[1] = pack_f16(x.z, x.w);
            afr[ng][kb].u[2] = pack_f16(y.x, y.y);
            afr[ng][kb].u[3] = pack_f16(y.z, y.w);
        }
    }

    const float SCALE_Q = 0.25f * 1.44269504f;   // 16^-0.5 * log2(e)
    uint32 kpk[4][2][4];                         // K results held for V pass

    #pragma unroll
    for (int mat = 0; mat < 3; ++mat) {
        const float* W = (mat == 0) ? Wq : (mat == 1) ? Wk : Wv;
        const float* bias = (mat == 0) ? bq : (mat == 1) ? bk : bv;

        // ---- transpose W (f32 [k][n]) -> Wl (f16 kpairs [n][kp], swizzled)
        __syncthreads();                         // previous mat's reads done
        {
            const float4* W4 = reinterpret_cast<const float4*>(W);
            #pragma unroll
            for (int i0 = 0; i0 < 8; ++i0) {
                int i = t + i0 * 256;            // i = k2*32 + nq
                int k2 = i >> 5, nq = i & 31;
                float4 a = W4[(k2 * 2) * 32 + nq];
                float4 b = W4[(k2 * 2 + 1) * 32 + nq];
                int slot = k2 >> 2, rem = k2 & 3;
                #pragma unroll
                for (int e = 0; e < 4; ++e) {
                    int n = nq * 4 + e;
                    float lo = (e == 0) ? a.x : (e == 1) ? a.y : (e == 2) ? a.z : a.w;
                    float hi = (e == 0) ? b.x : (e == 1) ? b.y : (e == 2) ? b.z : b.w;
                    Wl[n * 64 + ((slot ^ (n & 7)) << 2) + rem] = pack_f16(lo, hi);
                }
            }
        }
        __syncthreads();

        #pragma unroll
        for (int tp = 0; tp < 4; ++tp) {         // col-tile pair {tp, tp+4}
            const int c = tp * 16 + r;           // pair col (c, c+64)

            frag_u bfr[2][4];                    // [tti][kb]
            #pragma unroll
            for (int tti = 0; tti < 2; ++tti)
                #pragma unroll
                for (int kb = 0; kb < 4; ++kb) {
                    int n = (tp + 4 * tti) * 16 + r;
                    int s = kb * 4 + g;
                    bfr[tti][kb].q = *reinterpret_cast<const uint4*>(
                        &Wl[n * 64 + ((s ^ (n & 7)) << 2)]);
                }

            f32x4 acc[2][2];
            #pragma unroll
            for (int ng = 0; ng < 2; ++ng)
                #pragma unroll
                for (int tti = 0; tti < 2; ++tti)
                    acc[ng][tti] = (f32x4){0.f, 0.f, 0.f, 0.f};

            #pragma unroll
            for (int ng = 0; ng < 2; ++ng)
                #pragma unroll
                for (int tti = 0; tti < 2; ++tti)
                    #pragma unroll
                    for (int kb = 0; kb < 4; ++kb)
                        acc[ng][tti] = __builtin_amdgcn_mfma_f32_16x16x32_f16(
                            afr[ng][kb].h, bfr[tti][kb].h, acc[ng][tti], 0, 0, 0);

            // C/D map: col=lane&15, row=g*4+reg
            float blo = bias[c], bhi = bias[c + 64];
            #pragma unroll
            for (int ng = 0; ng < 2; ++ng) {
                #pragma unroll
                for (int reg = 0; reg < 4; ++reg) {
                    int node = rbase + ng * 16 + g * 4 + reg;
                    float lo = acc[ng][0][reg] + blo;
                    float hi = acc[ng][1][reg] + bhi;
                    if (mat == 0) {
                        if (node < N)
                            Qp[(size_t)node * 64 + c] = pack_f16(lo * SCALE_Q, hi * SCALE_Q);
                    } else if (mat == 1) {
                        kpk[tp][ng][reg] = pack_f16(lo, hi);
                    } else {
                        if (node < N)
                            KV[(size_t)node * 64 + c] =
                                make_uint2(kpk[tp][ng][reg], pack_f16(lo, hi));
                    }
                }
            }
        }
    }
}

// ---- fused edge stage: lane = (edge-slot, head); 2-wave blocks ------------
__global__ __launch_bounds__(128) void edge_attn_kernel(
    const uint32* __restrict__ Qp, const uint2* __restrict__ KV,
    const int* __restrict__ rp, const int* __restrict__ col,
    float* __restrict__ out, int N)
{
    const int lane = threadIdx.x & 63;
    const int node = blockIdx.x * 2 + (threadIdx.x >> 6);
    if (node >= N) return;
    const int hh   = lane & 7;      // head
    const int slot = lane >> 3;     // edge slot within group of 8

    const int start = rp[node], end = rp[node + 1];
    float* outp = out + (size_t)node * 128;
    if (start >= end) { outp[lane] = 0.f; outp[lane + 64] = 0.f; return; }
    const int last = end - 1;

    // Q for head hh: 8 packed f16 pairs (broadcast across slots)
    uint32 q[8];
    {
        const uint32* qrow = Qp + (size_t)node * 64;
        #pragma unroll
        for (int i = 0; i < 8; ++i) q[i] = qrow[hh + 8 * i];
    }

    float z = 0.f;
    float acc[16];
    #pragma unroll
    for (int i = 0; i < 16; ++i) acc[i] = 0.f;

    uint2 bufA[8], bufB[8];
    #define LOADG(buf, c0) { \
        const uint2* kvr = KV + (size_t)(c0) * 64; \
        _Pragma("unroll") \
        for (int i = 0; i < 8; ++i) (buf)[i] = kvr[hh + 8 * i]; }
    #define PROC(buf, gb) { \
        float s = 0.f; \
        _Pragma("unroll") \
        for (int i = 0; i < 8; ++i) s = dot2acc(q[i], (buf)[i].x, s); \
        float p = ((gb) + slot < end) ? __builtin_amdgcn_exp2f(s) : 0.f; \
        z += p; \
        _Pragma("unroll") \
        for (int i = 0; i < 8; ++i) { \
            f16x2 hv = __builtin_bit_cast(f16x2, (buf)[i].y); \
            acc[i]     = fmaf(p, (float)hv[0], acc[i]); \
            acc[8 + i] = fmaf(p, (float)hv[1], acc[8 + i]); } }

    int cA = col[min(start + slot, last)];
    int cB = col[min(start + 8 + slot, last)];
    LOADG(bufA, cA);
    int gb = start;
    while (true) {
        LOADG(bufB, cB);
        cA = col[min(gb + 16 + slot, last)];
        PROC(bufA, gb);
        gb += 8;
        if (gb >= end) break;
        LOADG(bufA, cA);
        cB = col[min(gb + 16 + slot, last)];
        PROC(bufB, gb);
        gb += 8;
        if (gb >= end) break;
    }

    // butterfly reduce across the 8 edge slots (xor lane bits 3..5)
    #pragma unroll
    for (int m = 8; m <= 32; m <<= 1) {
        z += __shfl_xor(z, m);
        #pragma unroll
        for (int i = 0; i < 16; ++i) acc[i] += __shfl_xor(acc[i], m);
    }

    // out flat idx = d*8 + h: lane writes d=slot and d=slot+8
    const float rz = 1.0f / z;
    outp[lane]      = acc[slot] * rz;
    outp[lane + 64] = acc[8 + slot] * rz;
}

extern "C" void kernel_launch(void* const* d_in, const int* in_sizes, int n_in,
                              void* d_out, int out_size, void* d_ws, size_t ws_size,
                              hipStream_t stream)
{
    const float* h  = (const float*)d_in[0];
    const float* Wq = (const float*)d_in[1];
    const float* bq = (const float*)d_in[2];
    const float* Wk = (const float*)d_in[3];
    const float* bk = (const float*)d_in[4];
    const float* Wv = (const float*)d_in[5];
    const float* bv = (const float*)d_in[6];
    const int* row  = (const int*)d_in[7];
    const int* col  = (const int*)d_in[8];
    float* out = (float*)d_out;

    const int N = in_sizes[0] / 128;
    const int E = in_sizes[7];

    // ws: KV (N*64 uint2) | Qp (N*64 u32) | rp (N+1)
    uint2*  KV = (uint2*)d_ws;
    uint32* Qp = (uint32*)(KV + (size_t)N * 64);
    int*    rp = (int*)(Qp + (size_t)N * 64);

    const int PB = (N + 127) / 128;              // proj blocks
    const int rp_blocks = (N + 1 + 255) / 256;   // row_ptr tail blocks

    proj_mfma_kernel<<<PB + rp_blocks, 256, 0, stream>>>(
        h, Wq, Wk, Wv, bq, bk, bv, Qp, KV, row, rp, N, E, PB);
    edge_attn_kernel<<<(N + 1) / 2, 128, 0, stream>>>(Qp, KV, rp, col, out, N);
}